// Round 1
// baseline (1150.165 us; speedup 1.0000x reference)
//
#include <hip/hip_runtime.h>
#include <hip/hip_bf16.h>
#include <stdint.h>

#define EMB    32
#define BATCH  128
#define NU     200000
#define KSEL   50000
#define XCOLS  33

// ---------------- prep: s_pre = x[:,1:] @ rp.T ; iid_emb gather ; base16 sample ----------
__global__ void prep_kernel(const float* __restrict__ x,
                            const float* __restrict__ iid_w,
                            const float* __restrict__ rp,
                            const float* __restrict__ uid,
                            float* __restrict__ s_pre,
                            float* __restrict__ iid_emb,
                            uint32_t* __restrict__ base16) {
    const int b = blockIdx.x;
    const int t = threadIdx.x;          // 64 threads
    __shared__ float xr[EMB];
    if (t < EMB) xr[t] = x[b * XCOLS + 1 + t];
    __syncthreads();
    if (t < EMB) {
        float acc = 0.f;
        #pragma unroll
        for (int k = 0; k < EMB; ++k) acc += xr[k] * rp[t * EMB + k];
        s_pre[b * EMB + t] = acc;
    } else {
        const int d = t - EMB;
        const int iid = (int)x[b * XCOLS];
        iid_emb[b * EMB + d] = iid_w[(size_t)iid * EMB + d];
    }
    __syncthreads();
    if (t == 0) {
        float dot = 0.f;
        #pragma unroll
        for (int k = 0; k < EMB; ++k) dot += s_pre[b * EMB + k] * uid[k];
        const uint32_t bits = __float_as_uint(fabsf(dot - 4.0f));
        const uint32_t hi = bits >> 16;
        base16[b] = (hi > 128u) ? (hi - 128u) : 0u;
    }
}

// ---------------- zero scratch ----------------
__global__ void zero_kernel(uint32_t* __restrict__ p, int n) {
    int i = blockIdx.x * blockDim.x + threadIdx.x;
    if (i < n) p[i] = 0u;
}

// ---------------- sweep1: per-row hist over clamped (bits>>16 - base16) ----------------
__global__ __launch_bounds__(256)
void sweep1_kernel(const float* __restrict__ s_pre,
                   const float* __restrict__ uid,
                   const uint32_t* __restrict__ base16,
                   uint32_t* __restrict__ ghist,
                   int jchunk) {
    extern __shared__ uint32_t hist[];   // [128][257] padded
    const int t  = threadIdx.x;
    const int b  = t & 127;
    const int jl = t >> 7;
    for (int i = t; i < 128 * 257; i += 256) hist[i] = 0u;
    float s[EMB];
    #pragma unroll
    for (int d = 0; d < EMB; ++d) s[d] = s_pre[b * EMB + d];
    const uint32_t base = base16[b];
    __syncthreads();
    const int j0 = blockIdx.x * jchunk;
    const int jend = min(j0 + jchunk, NU);
    for (int j = j0 + jl; j < jend; j += 2) {
        const float4* u4 = (const float4*)(uid + (size_t)j * EMB);
        float dot = 0.f;
        #pragma unroll
        for (int q = 0; q < 8; ++q) {
            float4 u = u4[q];
            dot += s[4*q+0]*u.x + s[4*q+1]*u.y + s[4*q+2]*u.z + s[4*q+3]*u.w;
        }
        const uint32_t bits = __float_as_uint(fabsf(dot - 4.0f));
        int digit = (int)(bits >> 16) - (int)base;
        digit = digit < 0 ? 0 : (digit > 255 ? 255 : digit);
        atomicAdd(&hist[b * 257 + digit], 1u);
    }
    __syncthreads();
    for (int i = t; i < 128 * 256; i += 256) {
        const int row = i >> 8, dig = i & 255;
        const uint32_t c = hist[row * 257 + dig];
        if (c) atomicAdd(&ghist[i], c);
    }
}

// ---------------- scan1: pick 16-bit prefix + residual target m2 ----------------
__global__ void scan1_kernel(const uint32_t* __restrict__ ghist,
                             const uint32_t* __restrict__ base16,
                             uint32_t* __restrict__ prefix16,
                             uint32_t* __restrict__ m2) {
    const int b = threadIdx.x;           // 128 threads, 1 block
    uint32_t cum = 0, before = 0;
    int c1 = 255;
    for (int d = 0; d < 256; ++d) {
        const uint32_t c = ghist[b * 256 + d];
        if (cum + c >= (uint32_t)KSEL) { c1 = d; before = cum; break; }
        cum += c;
        if (d == 255) before = cum;      // unreachable for valid data
    }
    prefix16[b] = base16[b] + (uint32_t)c1;
    m2[b] = (uint32_t)KSEL - before;
}

// ---------------- sweep2: sum vals strictly below prefix; append prefix-match candidates --
__global__ __launch_bounds__(256)
void sweep2_kernel(const float* __restrict__ s_pre,
                   const float* __restrict__ iid_emb,
                   const float* __restrict__ uid,
                   const uint32_t* __restrict__ prefix16,
                   uint32_t* __restrict__ eq_cnt,
                   float* __restrict__ sum_below,
                   uint64_t* __restrict__ cand,
                   int cap, int jchunk) {
    __shared__ float sums[128];
    const int t  = threadIdx.x;
    const int b  = t & 127;
    const int jl = t >> 7;
    if (t < 128) sums[t] = 0.f;
    float s[EMB], e[EMB];
    #pragma unroll
    for (int d = 0; d < EMB; ++d) { s[d] = s_pre[b*EMB+d]; e[d] = iid_emb[b*EMB+d]; }
    const uint32_t pfx = prefix16[b];
    __syncthreads();
    float local = 0.f;
    const int j0 = blockIdx.x * jchunk;
    const int jend = min(j0 + jchunk, NU);
    for (int j = j0 + jl; j < jend; j += 2) {
        const float4* u4 = (const float4*)(uid + (size_t)j * EMB);
        float dot = 0.f, dv = 0.f;
        #pragma unroll
        for (int q = 0; q < 8; ++q) {
            float4 u = u4[q];
            dot += s[4*q+0]*u.x + s[4*q+1]*u.y + s[4*q+2]*u.z + s[4*q+3]*u.w;
            dv  += e[4*q+0]*u.x + e[4*q+1]*u.y + e[4*q+2]*u.z + e[4*q+3]*u.w;
        }
        const uint32_t bits = __float_as_uint(fabsf(dot - 4.0f));
        const uint32_t hi = bits >> 16;
        if (hi < pfx) {
            local += dv;
        } else if (hi == pfx) {
            const uint32_t pos = atomicAdd(&eq_cnt[b], 1u);
            if (pos < (uint32_t)cap)
                cand[(size_t)b * cap + pos] = ((uint64_t)bits << 32) | (uint32_t)j;
        }
    }
    atomicAdd(&sums[b], local);
    __syncthreads();
    if (t < 128 && sums[t] != 0.f) atomicAdd(&sum_below[t], sums[t]);
}

// ---------------- finalize: refine low 16 bits among candidates, handle ties, output ------
__global__ __launch_bounds__(256)
void final_kernel(const float* __restrict__ iid_emb,
                  const float* __restrict__ uid,
                  const uint32_t* __restrict__ m2_,
                  const uint32_t* __restrict__ eq_cnt,
                  const float* __restrict__ sum_below,
                  const uint64_t* __restrict__ cand,
                  int cap, float* __restrict__ out) {
    const int b = blockIdx.x;
    const int t = threadIdx.x;           // 256 threads
    __shared__ uint32_t hist[256];
    __shared__ float e[EMB];
    __shared__ uint32_t tie[128];
    __shared__ uint32_t tiecnt, sc2, sm3, sc3, sm4;
    __shared__ float fsum;
    if (t < EMB) e[t] = iid_emb[b * EMB + t];
    if (t == 0) { tiecnt = 0u; fsum = 0.f; }
    hist[t] = 0u;
    __syncthreads();
    const uint32_t ec = eq_cnt[b];
    const int cnt = (int)(ec < (uint32_t)cap ? ec : (uint32_t)cap);
    const uint64_t* cb = cand + (size_t)b * cap;

    // phase A: hist over bits[15:8]
    for (int i = t; i < cnt; i += 256) {
        const uint32_t low16 = (uint32_t)(cb[i] >> 32) & 0xFFFFu;
        atomicAdd(&hist[low16 >> 8], 1u);
    }
    __syncthreads();
    if (t == 0) {
        const uint32_t m2v = m2_[b];
        uint32_t cum = 0, before = 0; int c2 = 255;
        for (int d = 0; d < 256; ++d) {
            const uint32_t c = hist[d];
            if (cum + c >= m2v) { c2 = d; before = cum; break; }
            cum += c;
        }
        sc2 = (uint32_t)c2; sm3 = m2v - before;
    }
    __syncthreads();
    const uint32_t c2 = sc2;
    hist[t] = 0u;
    __syncthreads();

    // phase B: hist over bits[7:0] among matching
    for (int i = t; i < cnt; i += 256) {
        const uint32_t low16 = (uint32_t)(cb[i] >> 32) & 0xFFFFu;
        if ((low16 >> 8) == c2) atomicAdd(&hist[low16 & 255u], 1u);
    }
    __syncthreads();
    if (t == 0) {
        const uint32_t m3 = sm3;
        uint32_t cum = 0, before = 0; int c3 = 255;
        for (int d = 0; d < 256; ++d) {
            const uint32_t c = hist[d];
            if (cum + c >= m3) { c3 = d; before = cum; break; }
            cum += c;
        }
        sc3 = (uint32_t)c3; sm4 = m3 - before;
    }
    __syncthreads();
    const uint32_t T16 = (c2 << 8) | sc3;

    // phase C: sum vals strictly below exact threshold; collect ties
    float local = 0.f;
    for (int i = t; i < cnt; i += 256) {
        const uint64_t cv = cb[i];
        const uint32_t low16 = (uint32_t)(cv >> 32) & 0xFFFFu;
        if (low16 < T16) {
            const uint32_t j = (uint32_t)cv;
            const float4* u4 = (const float4*)(uid + (size_t)j * EMB);
            float dv = 0.f;
            #pragma unroll
            for (int q = 0; q < 8; ++q) {
                float4 u = u4[q];
                dv += e[4*q+0]*u.x + e[4*q+1]*u.y + e[4*q+2]*u.z + e[4*q+3]*u.w;
            }
            local += dv;
        } else if (low16 == T16) {
            const uint32_t pos = atomicAdd(&tiecnt, 1u);
            if (pos < 128u) tie[pos] = (uint32_t)cv;
        }
    }
    atomicAdd(&fsum, local);
    __syncthreads();
    if (t == 0) {
        int tc = (int)(tiecnt < 128u ? tiecnt : 128u);
        for (int i = 1; i < tc; ++i) {           // insertion sort by index j
            const uint32_t v = tie[i]; int k = i - 1;
            while (k >= 0 && tie[k] > v) { tie[k+1] = tie[k]; --k; }
            tie[k+1] = v;
        }
        const int m4 = (int)sm4;
        float tsum = 0.f;
        for (int i = 0; i < m4 && i < tc; ++i) {
            const uint32_t j = tie[i];
            float dv = 0.f;
            for (int d = 0; d < EMB; ++d) dv += e[d] * uid[(size_t)j * EMB + d];
            tsum += dv;
        }
        out[b] = (sum_below[b] + fsum + tsum) / (float)KSEL;
    }
}

extern "C" void kernel_launch(void* const* d_in, const int* in_sizes, int n_in,
                              void* d_out, int out_size, void* d_ws, size_t ws_size,
                              hipStream_t stream) {
    const float* x     = (const float*)d_in[0];
    const float* uid   = (const float*)d_in[1];
    const float* iid_w = (const float*)d_in[2];
    const float* rp    = (const float*)d_in[3];
    float* out = (float*)d_out;

    char* ws = (char*)d_ws;
    // layout
    float*    s_pre    = (float*)(ws + 0);                 // 16384 B
    float*    iid_emb  = (float*)(ws + 16384);             // 16384 B
    uint32_t* ghist    = (uint32_t*)(ws + 32768);          // 131072 B
    uint32_t* eq_cnt   = (uint32_t*)(ws + 163840);         // 512 B
    float*    sum_below= (float*)(ws + 164352);            // 512 B
    uint32_t* base16   = (uint32_t*)(ws + 164864);         // 512 B
    uint32_t* prefix16 = (uint32_t*)(ws + 165376);         // 512 B
    uint32_t* m2       = (uint32_t*)(ws + 165888);         // 512 B
    uint64_t* cand     = (uint64_t*)(ws + 166400);

    long long cap_ll = ((long long)ws_size - 166400LL) / (128LL * 8LL);
    int cap = (int)(cap_ll > 16384 ? 16384 : (cap_ll < 1 ? 1 : cap_ll));

    // zero ghist + eq_cnt + sum_below (contiguous: 132096 B = 33024 u32)
    {
        const int n = 33024;
        zero_kernel<<<(n + 255) / 256, 256, 0, stream>>>((uint32_t*)(ws + 32768), n);
    }
    prep_kernel<<<BATCH, 64, 0, stream>>>(x, iid_w, rp, uid, s_pre, iid_emb, base16);

    const int JC1 = 784;
    const int G1 = (NU + JC1 - 1) / JC1;   // 256
    sweep1_kernel<<<G1, 256, 128 * 257 * 4, stream>>>(s_pre, uid, base16, ghist, JC1);

    scan1_kernel<<<1, 128, 0, stream>>>(ghist, base16, prefix16, m2);

    const int JC2 = 392;
    const int G2 = (NU + JC2 - 1) / JC2;   // 511
    sweep2_kernel<<<G2, 256, 0, stream>>>(s_pre, iid_emb, uid, prefix16,
                                          eq_cnt, sum_below, cand, cap, JC2);

    final_kernel<<<BATCH, 256, 0, stream>>>(iid_emb, uid, m2, eq_cnt, sum_below,
                                            cand, cap, out);
}

// Round 2
// 257.551 us; speedup vs baseline: 4.4658x; 4.4658x over previous
//
#include <hip/hip_runtime.h>
#include <hip/hip_bf16.h>
#include <stdint.h>

#define EMB    32
#define BATCH  128
#define NU     200000
#define KSEL   50000
#define XCOLS  33
#define TILE   64
#define SLOTS  64      // per-(block,b) LDS candidate slots; expected ~12, Poisson tail ~0

// ws layout
#define OFF_SPRE   0
#define OFF_IIDE   16384
#define OFF_GHIST  32768    // 128*256 u32 = 131072; reused as sum_part[256][128] f32 after scan1
#define OFF_BASE16 163840
#define OFF_PREFIX 164352
#define OFF_M2     164864
#define OFF_EQ     165376   // 128 counters, stride 16 u32 (64B) to avoid cacheline sharing
#define OFF_CAND   173568

// ---------------- prep: s_pre = x[:,1:] @ rp.T ; iid_emb gather ; base16 sample ----------
__global__ void prep_kernel(const float* __restrict__ x,
                            const float* __restrict__ iid_w,
                            const float* __restrict__ rp,
                            const float* __restrict__ uid,
                            float* __restrict__ s_pre,
                            float* __restrict__ iid_emb,
                            uint32_t* __restrict__ base16) {
    const int b = blockIdx.x;
    const int t = threadIdx.x;          // 64 threads
    __shared__ float xr[EMB];
    if (t < EMB) xr[t] = x[b * XCOLS + 1 + t];
    __syncthreads();
    if (t < EMB) {
        float acc = 0.f;
        #pragma unroll
        for (int k = 0; k < EMB; ++k) acc += xr[k] * rp[t * EMB + k];
        s_pre[b * EMB + t] = acc;
    } else {
        const int d = t - EMB;
        const int iid = (int)x[b * XCOLS];
        iid_emb[b * EMB + d] = iid_w[(size_t)iid * EMB + d];
    }
    __syncthreads();
    if (t == 0) {
        float dot = 0.f;
        #pragma unroll
        for (int k = 0; k < EMB; ++k) dot += s_pre[b * EMB + k] * uid[k];
        const uint32_t bits = __float_as_uint(fabsf(dot - 4.0f));
        const uint32_t hi = bits >> 16;
        base16[b] = (hi > 128u) ? (hi - 128u) : 0u;
    }
}

// ---------------- zero scratch ----------------
__global__ void zero_kernel(uint32_t* __restrict__ p, int n) {
    int i = blockIdx.x * blockDim.x + threadIdx.x;
    if (i < n) p[i] = 0u;
}

// ---------------- sweep1: LDS-staged, double-buffered key histogram ----------------
__global__ __launch_bounds__(1024)
void sweep1_kernel(const float* __restrict__ s_pre,
                   const float* __restrict__ uid,
                   const uint32_t* __restrict__ base16,
                   uint32_t* __restrict__ ghist,
                   int jchunk) {
    extern __shared__ uint32_t smem1[];
    uint32_t* hist = smem1;                        // 128*257 u32 (padded stride)
    float* tiles = (float*)(smem1 + 128 * 257);    // [2][TILE*EMB]
    const int t  = threadIdx.x;
    const int b  = t & 127;
    const int jl = t >> 7;                         // 0..7
    for (int i = t; i < 128 * 257; i += 1024) hist[i] = 0u;
    float s[EMB];
    #pragma unroll
    for (int d = 0; d < EMB; ++d) s[d] = s_pre[b * EMB + d];
    const uint32_t base = base16[b];

    const int j0 = blockIdx.x * jchunk;
    const int jend = min(j0 + jchunk, NU);
    const int nt = (jend - j0 + TILE - 1) / TILE;
    const int srow = t >> 4;                       // 0..63
    const int sq   = t & 15;                       // float2 slot

    {   // prologue: stage tile 0 into buf0
        const int j = j0 + srow;
        float2 v = make_float2(0.f, 0.f);
        if (j < NU) v = *(const float2*)(uid + (size_t)j * EMB + sq * 2);
        *(float2*)(tiles + srow * EMB + sq * 2) = v;
    }
    __syncthreads();

    for (int tt = 0; tt < nt; ++tt) {
        const int jt = j0 + tt * TILE;
        const bool has_next = (tt + 1 < nt);
        float2 vnext = make_float2(0.f, 0.f);
        if (has_next) {                            // issue-early: load hides under compute
            const int j = jt + TILE + srow;
            if (j < NU) vnext = *(const float2*)(uid + (size_t)j * EMB + sq * 2);
        }
        const float* tp = tiles + (tt & 1) * (TILE * EMB);
        const int lim = min(TILE, jend - jt);
        for (int jj = jl; jj < lim; jj += 8) {
            const float4* u4 = (const float4*)(tp + jj * EMB);
            float dot = 0.f;
            #pragma unroll
            for (int q = 0; q < 8; ++q) {
                float4 u = u4[q];
                dot += s[4*q+0]*u.x + s[4*q+1]*u.y + s[4*q+2]*u.z + s[4*q+3]*u.w;
            }
            const uint32_t bits = __float_as_uint(fabsf(dot - 4.0f));
            int digit = (int)(bits >> 16) - (int)base;
            digit = digit < 0 ? 0 : (digit > 255 ? 255 : digit);
            atomicAdd(&hist[b * 257 + digit], 1u);
        }
        if (has_next) {                            // write-late into the other buffer
            *(float2*)(tiles + ((tt + 1) & 1) * (TILE * EMB) + srow * EMB + sq * 2) = vnext;
        }
        __syncthreads();
    }
    // flush per-block hist to global (sparse-ish atomics)
    for (int i = t; i < 128 * 256; i += 1024) {
        const uint32_t c = hist[(i >> 8) * 257 + (i & 255)];
        if (c) atomicAdd(&ghist[i], c);
    }
}

// ---------------- scan1: pick 16-bit prefix + residual target m2 ----------------
__global__ void scan1_kernel(const uint32_t* __restrict__ ghist,
                             const uint32_t* __restrict__ base16,
                             uint32_t* __restrict__ prefix16,
                             uint32_t* __restrict__ m2) {
    const int b = threadIdx.x;           // 128 threads, 1 block
    uint32_t cum = 0, before = 0;
    int c1 = 255;
    for (int d = 0; d < 256; ++d) {
        const uint32_t c = ghist[b * 256 + d];
        if (cum + c >= (uint32_t)KSEL) { c1 = d; before = cum; break; }
        cum += c;
        if (d == 255) before = cum;
    }
    prefix16[b] = base16[b] + (uint32_t)c1;
    m2[b] = (uint32_t)KSEL - before;
}

// ---------------- sweep2: LDS-staged dual-dot; below-sum + candidate collection ----------
__global__ __launch_bounds__(1024)
void sweep2_kernel(const float* __restrict__ s_pre,
                   const float* __restrict__ iid_emb,
                   const float* __restrict__ uid,
                   const uint32_t* __restrict__ prefix16,
                   uint32_t* __restrict__ eq_cnt,
                   float* __restrict__ sum_part,
                   uint64_t* __restrict__ cand,
                   int cap, int jchunk) {
    extern __shared__ char smem2[];
    uint64_t* lcand = (uint64_t*)smem2;                          // 128*SLOTS*8 = 65536
    float*    tiles = (float*)(smem2 + 65536);                   // 16384
    uint32_t* lcnt  = (uint32_t*)(smem2 + 65536 + 16384);        // 512
    uint32_t* lbase = (uint32_t*)(smem2 + 65536 + 16384 + 512);  // 512
    float*    sums  = (float*)(smem2 + 65536 + 16384 + 1024);    // 4096
    const int t  = threadIdx.x;
    const int b  = t & 127;
    const int jl = t >> 7;
    if (t < 128) lcnt[t] = 0u;
    float s[EMB], e[EMB];
    #pragma unroll
    for (int d = 0; d < EMB; ++d) { s[d] = s_pre[b*EMB+d]; e[d] = iid_emb[b*EMB+d]; }
    const uint32_t pfx = prefix16[b];

    const int j0 = blockIdx.x * jchunk;
    const int jend = min(j0 + jchunk, NU);
    const int nt = (jend - j0 + TILE - 1) / TILE;
    const int srow = t >> 4;
    const int sq   = t & 15;

    {
        const int j = j0 + srow;
        float2 v = make_float2(0.f, 0.f);
        if (j < NU) v = *(const float2*)(uid + (size_t)j * EMB + sq * 2);
        *(float2*)(tiles + srow * EMB + sq * 2) = v;
    }
    __syncthreads();

    float local = 0.f;
    for (int tt = 0; tt < nt; ++tt) {
        const int jt = j0 + tt * TILE;
        const bool has_next = (tt + 1 < nt);
        float2 vnext = make_float2(0.f, 0.f);
        if (has_next) {
            const int j = jt + TILE + srow;
            if (j < NU) vnext = *(const float2*)(uid + (size_t)j * EMB + sq * 2);
        }
        const float* tp = tiles + (tt & 1) * (TILE * EMB);
        const int lim = min(TILE, jend - jt);
        for (int jj = jl; jj < lim; jj += 8) {
            const float4* u4 = (const float4*)(tp + jj * EMB);
            float dot = 0.f, dv = 0.f;
            #pragma unroll
            for (int q = 0; q < 8; ++q) {
                float4 u = u4[q];
                dot += s[4*q+0]*u.x + s[4*q+1]*u.y + s[4*q+2]*u.z + s[4*q+3]*u.w;
                dv  += e[4*q+0]*u.x + e[4*q+1]*u.y + e[4*q+2]*u.z + e[4*q+3]*u.w;
            }
            const uint32_t bits = __float_as_uint(fabsf(dot - 4.0f));
            const uint32_t hi = bits >> 16;
            if (hi < pfx) {
                local += dv;
            } else if (hi == pfx) {
                const uint32_t pos = atomicAdd(&lcnt[b], 1u);
                const uint64_t pk = ((uint64_t)bits << 32) | (uint32_t)(jt + jj);
                if (pos < (uint32_t)SLOTS) {
                    lcand[b * SLOTS + pos] = pk;
                } else {  // overflow fallback (exactness under pathological data)
                    const uint32_t g = atomicAdd(&eq_cnt[b * 16], 1u);
                    if (g < (uint32_t)cap) cand[(size_t)b * cap + g] = pk;
                }
            }
        }
        if (has_next) {
            *(float2*)(tiles + ((tt + 1) & 1) * (TILE * EMB) + srow * EMB + sq * 2) = vnext;
        }
        __syncthreads();
    }
    sums[t] = local;                       // unique slot per thread: t = jl*128 + b
    __syncthreads();
    if (t < 128) {
        float acc = 0.f;
        #pragma unroll
        for (int l = 0; l < 8; ++l) acc += sums[l * 128 + t];
        sum_part[blockIdx.x * 128 + t] = acc;             // deterministic partials
        const uint32_t n = min(lcnt[t], (uint32_t)SLOTS);
        lbase[t] = atomicAdd(&eq_cnt[t * 16], n);         // one reservation per (block,b)
    }
    __syncthreads();
    for (int i = t; i < 128 * SLOTS; i += 1024) {
        const int bb = i >> 6;             // SLOTS == 64
        const int sl = i & 63;
        if (sl < (int)min(lcnt[bb], (uint32_t)SLOTS)) {
            const uint32_t p = lbase[bb] + (uint32_t)sl;
            if (p < (uint32_t)cap) cand[(size_t)bb * cap + p] = lcand[i];
        }
    }
}

// ---------------- finalize: refine low 16 bits among candidates, ties, output ------
__global__ __launch_bounds__(256)
void final_kernel(const float* __restrict__ iid_emb,
                  const float* __restrict__ uid,
                  const uint32_t* __restrict__ m2_,
                  const uint32_t* __restrict__ eq_cnt,
                  const float* __restrict__ sum_part,
                  const uint64_t* __restrict__ cand,
                  int cap, float* __restrict__ out) {
    const int b = blockIdx.x;
    const int t = threadIdx.x;           // 256 threads
    __shared__ float red[256];
    __shared__ uint32_t hist[256];
    __shared__ float e[EMB];
    __shared__ uint32_t tie[128];
    __shared__ uint32_t tiecnt, sc2, sm3, sc3, sm4;
    __shared__ float sbelow;
    if (t < EMB) e[t] = iid_emb[b * EMB + t];
    if (t == 0) tiecnt = 0u;
    hist[t] = 0u;
    red[t] = sum_part[t * 128 + b];      // 256 block partials for row b
    __syncthreads();
    for (int s = 128; s > 0; s >>= 1) { if (t < s) red[t] += red[t + s]; __syncthreads(); }
    if (t == 0) sbelow = red[0];
    __syncthreads();

    const uint32_t ec = eq_cnt[b * 16];
    const int cnt = (int)(ec < (uint32_t)cap ? ec : (uint32_t)cap);
    const uint64_t* cb = cand + (size_t)b * cap;

    // phase A: hist over bits[15:8]
    for (int i = t; i < cnt; i += 256) {
        const uint32_t low16 = (uint32_t)(cb[i] >> 32) & 0xFFFFu;
        atomicAdd(&hist[low16 >> 8], 1u);
    }
    __syncthreads();
    if (t == 0) {
        const uint32_t m2v = m2_[b];
        uint32_t cum = 0, before = 0; int c2 = 255;
        for (int d = 0; d < 256; ++d) {
            const uint32_t c = hist[d];
            if (cum + c >= m2v) { c2 = d; before = cum; break; }
            cum += c;
        }
        sc2 = (uint32_t)c2; sm3 = m2v - before;
    }
    __syncthreads();
    const uint32_t c2 = sc2;
    hist[t] = 0u;
    __syncthreads();

    // phase B: hist over bits[7:0] among matching
    for (int i = t; i < cnt; i += 256) {
        const uint32_t low16 = (uint32_t)(cb[i] >> 32) & 0xFFFFu;
        if ((low16 >> 8) == c2) atomicAdd(&hist[low16 & 255u], 1u);
    }
    __syncthreads();
    if (t == 0) {
        const uint32_t m3 = sm3;
        uint32_t cum = 0, before = 0; int c3 = 255;
        for (int d = 0; d < 256; ++d) {
            const uint32_t c = hist[d];
            if (cum + c >= m3) { c3 = d; before = cum; break; }
            cum += c;
        }
        sc3 = (uint32_t)c3; sm4 = m3 - before;
    }
    __syncthreads();
    const uint32_t T16 = (c2 << 8) | sc3;

    // phase C: sum vals strictly below exact threshold; collect ties
    float local = 0.f;
    for (int i = t; i < cnt; i += 256) {
        const uint64_t cv = cb[i];
        const uint32_t low16 = (uint32_t)(cv >> 32) & 0xFFFFu;
        if (low16 < T16) {
            const uint32_t j = (uint32_t)cv;
            const float4* u4 = (const float4*)(uid + (size_t)j * EMB);
            float dv = 0.f;
            #pragma unroll
            for (int q = 0; q < 8; ++q) {
                float4 u = u4[q];
                dv += e[4*q+0]*u.x + e[4*q+1]*u.y + e[4*q+2]*u.z + e[4*q+3]*u.w;
            }
            local += dv;
        } else if (low16 == T16) {
            const uint32_t pos = atomicAdd(&tiecnt, 1u);
            if (pos < 128u) tie[pos] = (uint32_t)cv;
        }
    }
    red[t] = local;
    __syncthreads();
    for (int s = 128; s > 0; s >>= 1) { if (t < s) red[t] += red[t + s]; __syncthreads(); }
    if (t == 0) {
        int tc = (int)(tiecnt < 128u ? tiecnt : 128u);
        for (int i = 1; i < tc; ++i) {           // insertion sort ties by index j
            const uint32_t v = tie[i]; int k = i - 1;
            while (k >= 0 && tie[k] > v) { tie[k+1] = tie[k]; --k; }
            tie[k+1] = v;
        }
        const int m4 = (int)sm4;
        float tsum = 0.f;
        for (int i = 0; i < m4 && i < tc; ++i) {
            const uint32_t j = tie[i];
            float dv = 0.f;
            for (int d = 0; d < EMB; ++d) dv += e[d] * uid[(size_t)j * EMB + d];
            tsum += dv;
        }
        out[b] = (sbelow + red[0] + tsum) / (float)KSEL;
    }
}

extern "C" void kernel_launch(void* const* d_in, const int* in_sizes, int n_in,
                              void* d_out, int out_size, void* d_ws, size_t ws_size,
                              hipStream_t stream) {
    const float* x     = (const float*)d_in[0];
    const float* uid   = (const float*)d_in[1];
    const float* iid_w = (const float*)d_in[2];
    const float* rp    = (const float*)d_in[3];
    float* out = (float*)d_out;

    char* ws = (char*)d_ws;
    float*    s_pre    = (float*)(ws + OFF_SPRE);
    float*    iid_emb  = (float*)(ws + OFF_IIDE);
    uint32_t* ghist    = (uint32_t*)(ws + OFF_GHIST);
    float*    sum_part = (float*)(ws + OFF_GHIST);     // overlay: reused after scan1
    uint32_t* base16   = (uint32_t*)(ws + OFF_BASE16);
    uint32_t* prefix16 = (uint32_t*)(ws + OFF_PREFIX);
    uint32_t* m2       = (uint32_t*)(ws + OFF_M2);
    uint32_t* eq_cnt   = (uint32_t*)(ws + OFF_EQ);
    uint64_t* cand     = (uint64_t*)(ws + OFF_CAND);

    long long cap_ll = ((long long)ws_size - OFF_CAND) / (128LL * 8LL);
    int cap = (int)(cap_ll > 16384 ? 16384 : (cap_ll < 1 ? 1 : cap_ll));

    // zero [ghist .. cand): ghist + base16/prefix/m2 + eq_cnt
    {
        const int n = (OFF_CAND - OFF_GHIST) / 4;      // 35200 u32
        zero_kernel<<<(n + 255) / 256, 256, 0, stream>>>((uint32_t*)(ws + OFF_GHIST), n);
    }
    prep_kernel<<<BATCH, 64, 0, stream>>>(x, iid_w, rp, uid, s_pre, iid_emb, base16);

    const int JC = 782;                                // ceil(200000/256)
    const int G  = 256;                                // 1 block per CU
    sweep1_kernel<<<G, 1024, 128*257*4 + 2*TILE*EMB*4, stream>>>(s_pre, uid, base16, ghist, JC);

    scan1_kernel<<<1, 128, 0, stream>>>(ghist, base16, prefix16, m2);

    sweep2_kernel<<<G, 1024, 65536 + 16384 + 1024 + 4096, stream>>>(s_pre, iid_emb, uid,
                                                                    prefix16, eq_cnt, sum_part,
                                                                    cand, cap, JC);

    final_kernel<<<BATCH, 256, 0, stream>>>(iid_emb, uid, m2, eq_cnt, sum_part,
                                            cand, cap, out);
}

// Round 3
// 210.879 us; speedup vs baseline: 5.4541x; 1.2213x over previous
//
#include <hip/hip_runtime.h>
#include <hip/hip_bf16.h>
#include <stdint.h>

#define EMB    32
#define BATCH  128
#define NU     200000
#define KSEL   50000
#define XCOLS  33
#define SLOTS  64

// ws layout
#define OFF_SPRE   0
#define OFF_IIDE   16384
#define OFF_GHIST  32768    // 128*256 u32 = 131072; reused as sum_part[256][128] f32 after scan1
#define OFF_BASE16 163840
#define OFF_PREFIX 164352
#define OFF_M2     164864
#define OFF_EQ     165376   // 128 counters, stride 16 u32 (64B)
#define OFF_CAND   173568

// ---------------- prep ----------------
__global__ void prep_kernel(const float* __restrict__ x,
                            const float* __restrict__ iid_w,
                            const float* __restrict__ rp,
                            const float* __restrict__ uid,
                            float* __restrict__ s_pre,
                            float* __restrict__ iid_emb,
                            uint32_t* __restrict__ base16) {
    const int b = blockIdx.x;
    const int t = threadIdx.x;          // 64 threads
    __shared__ float xr[EMB];
    if (t < EMB) xr[t] = x[b * XCOLS + 1 + t];
    __syncthreads();
    if (t < EMB) {
        float acc = 0.f;
        #pragma unroll
        for (int k = 0; k < EMB; ++k) acc += xr[k] * rp[t * EMB + k];
        s_pre[b * EMB + t] = acc;
    } else {
        const int d = t - EMB;
        const int iid = (int)x[b * XCOLS];
        iid_emb[b * EMB + d] = iid_w[(size_t)iid * EMB + d];
    }
    __syncthreads();
    if (t == 0) {
        float dot = 0.f;
        #pragma unroll
        for (int k = 0; k < EMB; ++k) dot += s_pre[b * EMB + k] * uid[k];
        const uint32_t bits = __float_as_uint(fabsf(dot - 4.0f));
        const uint32_t hi = bits >> 16;
        base16[b] = (hi > 128u) ? (hi - 128u) : 0u;
    }
}

// ---------------- zero scratch ----------------
__global__ void zero_kernel(uint32_t* __restrict__ p, int n) {
    int i = blockIdx.x * blockDim.x + threadIdx.x;
    if (i < n) p[i] = 0u;
}

// ---------------- sweep1: scalar-load u, no LDS staging; per-row key histogram -------
__global__ __launch_bounds__(1024)
void sweep1_kernel(const float* __restrict__ s_pre,
                   const float* __restrict__ uid,
                   const uint32_t* __restrict__ base16,
                   uint32_t* __restrict__ ghist,
                   int jchunk) {
    extern __shared__ uint32_t hist[];   // [128][257] padded
    const int t  = threadIdx.x;
    const int b  = t & 127;
    const int jl = t >> 7;               // 0..7, wave-uniform
    for (int i = t; i < 128 * 257; i += 1024) hist[i] = 0u;
    float s[EMB];
    #pragma unroll
    for (int d = 0; d < EMB; ++d) s[d] = s_pre[b * EMB + d];
    const uint32_t base = base16[b];
    __syncthreads();

    const int j0 = blockIdx.x * jchunk;
    const int jend = min(j0 + jchunk, NU);
    int j = j0 + jl;
    for (; j + 8 < jend; j += 16) {
        const int ju = __builtin_amdgcn_readfirstlane(j);    // wave-uniform -> SGPR addr
        const float* up0 = uid + (size_t)ju * EMB;
        const float* up1 = up0 + 8 * EMB;
        float d0 = 0.f, d1 = 0.f;
        #pragma unroll
        for (int k = 0; k < EMB; ++k) {
            d0 += s[k] * up0[k];
            d1 += s[k] * up1[k];
        }
        const uint32_t bits0 = __float_as_uint(fabsf(d0 - 4.0f));
        const uint32_t bits1 = __float_as_uint(fabsf(d1 - 4.0f));
        int dg0 = (int)(bits0 >> 16) - (int)base; dg0 = dg0 < 0 ? 0 : (dg0 > 255 ? 255 : dg0);
        int dg1 = (int)(bits1 >> 16) - (int)base; dg1 = dg1 < 0 ? 0 : (dg1 > 255 ? 255 : dg1);
        atomicAdd(&hist[b * 257 + dg0], 1u);
        atomicAdd(&hist[b * 257 + dg1], 1u);
    }
    for (; j < jend; j += 8) {
        const int ju = __builtin_amdgcn_readfirstlane(j);
        const float* up0 = uid + (size_t)ju * EMB;
        float d0 = 0.f;
        #pragma unroll
        for (int k = 0; k < EMB; ++k) d0 += s[k] * up0[k];
        const uint32_t bits0 = __float_as_uint(fabsf(d0 - 4.0f));
        int dg0 = (int)(bits0 >> 16) - (int)base; dg0 = dg0 < 0 ? 0 : (dg0 > 255 ? 255 : dg0);
        atomicAdd(&hist[b * 257 + dg0], 1u);
    }
    __syncthreads();
    for (int i = t; i < 128 * 256; i += 1024) {
        const uint32_t c = hist[(i >> 8) * 257 + (i & 255)];
        if (c) atomicAdd(&ghist[i], c);
    }
}

// ---------------- scan1 ----------------
__global__ void scan1_kernel(const uint32_t* __restrict__ ghist,
                             const uint32_t* __restrict__ base16,
                             uint32_t* __restrict__ prefix16,
                             uint32_t* __restrict__ m2) {
    const int b = threadIdx.x;           // 128 threads, 1 block
    uint32_t cum = 0, before = 0;
    int c1 = 255;
    for (int d = 0; d < 256; ++d) {
        const uint32_t c = ghist[b * 256 + d];
        if (cum + c >= (uint32_t)KSEL) { c1 = d; before = cum; break; }
        cum += c;
        if (d == 255) before = cum;
    }
    prefix16[b] = base16[b] + (uint32_t)c1;
    m2[b] = (uint32_t)KSEL - before;
}

// ---------------- sweep2: scalar-load u dual-dot; below-sum + candidates ----------
__global__ __launch_bounds__(1024)
void sweep2_kernel(const float* __restrict__ s_pre,
                   const float* __restrict__ iid_emb,
                   const float* __restrict__ uid,
                   const uint32_t* __restrict__ prefix16,
                   uint32_t* __restrict__ eq_cnt,
                   float* __restrict__ sum_part,
                   uint64_t* __restrict__ cand,
                   int cap, int jchunk) {
    extern __shared__ char smem2[];
    uint64_t* lcand = (uint64_t*)smem2;                   // 65536
    uint32_t* lcnt  = (uint32_t*)(smem2 + 65536);         // 512
    uint32_t* lbase = (uint32_t*)(smem2 + 66048);         // 512
    float*    sums  = (float*)(smem2 + 66560);            // 4096
    const int t  = threadIdx.x;
    const int b  = t & 127;
    const int jl = t >> 7;               // wave-uniform
    if (t < 128) lcnt[t] = 0u;
    float s[EMB], e[EMB];
    #pragma unroll
    for (int d = 0; d < EMB; ++d) { s[d] = s_pre[b*EMB+d]; e[d] = iid_emb[b*EMB+d]; }
    const uint32_t pfx = prefix16[b];
    __syncthreads();

    const int j0 = blockIdx.x * jchunk;
    const int jend = min(j0 + jchunk, NU);
    float local = 0.f;
    int j = j0 + jl;
    for (; j + 8 < jend; j += 16) {
        const int ju = __builtin_amdgcn_readfirstlane(j);
        const float* up0 = uid + (size_t)ju * EMB;
        const float* up1 = up0 + 8 * EMB;
        float d0 = 0.f, v0 = 0.f, d1 = 0.f, v1 = 0.f;
        #pragma unroll
        for (int k = 0; k < EMB; ++k) {
            const float u0 = up0[k], u1 = up1[k];
            d0 += s[k] * u0;  v0 += e[k] * u0;
            d1 += s[k] * u1;  v1 += e[k] * u1;
        }
        const uint32_t bits0 = __float_as_uint(fabsf(d0 - 4.0f));
        const uint32_t bits1 = __float_as_uint(fabsf(d1 - 4.0f));
        const uint32_t hi0 = bits0 >> 16, hi1 = bits1 >> 16;
        if (hi0 < pfx) local += v0;
        else if (hi0 == pfx) {
            const uint32_t pos = atomicAdd(&lcnt[b], 1u);
            const uint64_t pk = ((uint64_t)bits0 << 32) | (uint32_t)j;
            if (pos < (uint32_t)SLOTS) lcand[b * SLOTS + pos] = pk;
            else {
                const uint32_t g = atomicAdd(&eq_cnt[b * 16], 1u);
                if (g < (uint32_t)cap) cand[(size_t)b * cap + g] = pk;
            }
        }
        if (hi1 < pfx) local += v1;
        else if (hi1 == pfx) {
            const uint32_t pos = atomicAdd(&lcnt[b], 1u);
            const uint64_t pk = ((uint64_t)bits1 << 32) | (uint32_t)(j + 8);
            if (pos < (uint32_t)SLOTS) lcand[b * SLOTS + pos] = pk;
            else {
                const uint32_t g = atomicAdd(&eq_cnt[b * 16], 1u);
                if (g < (uint32_t)cap) cand[(size_t)b * cap + g] = pk;
            }
        }
    }
    for (; j < jend; j += 8) {
        const int ju = __builtin_amdgcn_readfirstlane(j);
        const float* up0 = uid + (size_t)ju * EMB;
        float d0 = 0.f, v0 = 0.f;
        #pragma unroll
        for (int k = 0; k < EMB; ++k) {
            const float u0 = up0[k];
            d0 += s[k] * u0;  v0 += e[k] * u0;
        }
        const uint32_t bits0 = __float_as_uint(fabsf(d0 - 4.0f));
        const uint32_t hi0 = bits0 >> 16;
        if (hi0 < pfx) local += v0;
        else if (hi0 == pfx) {
            const uint32_t pos = atomicAdd(&lcnt[b], 1u);
            const uint64_t pk = ((uint64_t)bits0 << 32) | (uint32_t)j;
            if (pos < (uint32_t)SLOTS) lcand[b * SLOTS + pos] = pk;
            else {
                const uint32_t g = atomicAdd(&eq_cnt[b * 16], 1u);
                if (g < (uint32_t)cap) cand[(size_t)b * cap + g] = pk;
            }
        }
    }
    sums[t] = local;                       // unique slot per thread
    __syncthreads();
    if (t < 128) {
        float acc = 0.f;
        #pragma unroll
        for (int l = 0; l < 8; ++l) acc += sums[l * 128 + t];
        sum_part[blockIdx.x * 128 + t] = acc;
        const uint32_t n = min(lcnt[t], (uint32_t)SLOTS);
        lbase[t] = atomicAdd(&eq_cnt[t * 16], n);
    }
    __syncthreads();
    for (int i = t; i < 128 * SLOTS; i += 1024) {
        const int bb = i >> 6;             // SLOTS == 64
        const int sl = i & 63;
        if (sl < (int)min(lcnt[bb], (uint32_t)SLOTS)) {
            const uint32_t p = lbase[bb] + (uint32_t)sl;
            if (p < (uint32_t)cap) cand[(size_t)bb * cap + p] = lcand[i];
        }
    }
}

// ---------------- finalize ----------------
__global__ __launch_bounds__(256)
void final_kernel(const float* __restrict__ iid_emb,
                  const float* __restrict__ uid,
                  const uint32_t* __restrict__ m2_,
                  const uint32_t* __restrict__ eq_cnt,
                  const float* __restrict__ sum_part,
                  const uint64_t* __restrict__ cand,
                  int cap, float* __restrict__ out) {
    const int b = blockIdx.x;
    const int t = threadIdx.x;           // 256 threads
    __shared__ float red[256];
    __shared__ uint32_t hist[256];
    __shared__ float e[EMB];
    __shared__ uint32_t tie[128];
    __shared__ uint32_t tiecnt, sc2, sm3, sc3, sm4;
    __shared__ float sbelow;
    if (t < EMB) e[t] = iid_emb[b * EMB + t];
    if (t == 0) tiecnt = 0u;
    hist[t] = 0u;
    red[t] = sum_part[t * 128 + b];
    __syncthreads();
    for (int s = 128; s > 0; s >>= 1) { if (t < s) red[t] += red[t + s]; __syncthreads(); }
    if (t == 0) sbelow = red[0];
    __syncthreads();

    const uint32_t ec = eq_cnt[b * 16];
    const int cnt = (int)(ec < (uint32_t)cap ? ec : (uint32_t)cap);
    const uint64_t* cb = cand + (size_t)b * cap;

    for (int i = t; i < cnt; i += 256) {
        const uint32_t low16 = (uint32_t)(cb[i] >> 32) & 0xFFFFu;
        atomicAdd(&hist[low16 >> 8], 1u);
    }
    __syncthreads();
    if (t == 0) {
        const uint32_t m2v = m2_[b];
        uint32_t cum = 0, before = 0; int c2 = 255;
        for (int d = 0; d < 256; ++d) {
            const uint32_t c = hist[d];
            if (cum + c >= m2v) { c2 = d; before = cum; break; }
            cum += c;
        }
        sc2 = (uint32_t)c2; sm3 = m2v - before;
    }
    __syncthreads();
    const uint32_t c2 = sc2;
    hist[t] = 0u;
    __syncthreads();

    for (int i = t; i < cnt; i += 256) {
        const uint32_t low16 = (uint32_t)(cb[i] >> 32) & 0xFFFFu;
        if ((low16 >> 8) == c2) atomicAdd(&hist[low16 & 255u], 1u);
    }
    __syncthreads();
    if (t == 0) {
        const uint32_t m3 = sm3;
        uint32_t cum = 0, before = 0; int c3 = 255;
        for (int d = 0; d < 256; ++d) {
            const uint32_t c = hist[d];
            if (cum + c >= m3) { c3 = d; before = cum; break; }
            cum += c;
        }
        sc3 = (uint32_t)c3; sm4 = m3 - before;
    }
    __syncthreads();
    const uint32_t T16 = (c2 << 8) | sc3;

    float local = 0.f;
    for (int i = t; i < cnt; i += 256) {
        const uint64_t cv = cb[i];
        const uint32_t low16 = (uint32_t)(cv >> 32) & 0xFFFFu;
        if (low16 < T16) {
            const uint32_t j = (uint32_t)cv;
            const float4* u4 = (const float4*)(uid + (size_t)j * EMB);
            float dv = 0.f;
            #pragma unroll
            for (int q = 0; q < 8; ++q) {
                float4 u = u4[q];
                dv += e[4*q+0]*u.x + e[4*q+1]*u.y + e[4*q+2]*u.z + e[4*q+3]*u.w;
            }
            local += dv;
        } else if (low16 == T16) {
            const uint32_t pos = atomicAdd(&tiecnt, 1u);
            if (pos < 128u) tie[pos] = (uint32_t)cv;
        }
    }
    red[t] = local;
    __syncthreads();
    for (int s = 128; s > 0; s >>= 1) { if (t < s) red[t] += red[t + s]; __syncthreads(); }
    if (t == 0) {
        int tc = (int)(tiecnt < 128u ? tiecnt : 128u);
        for (int i = 1; i < tc; ++i) {
            const uint32_t v = tie[i]; int k = i - 1;
            while (k >= 0 && tie[k] > v) { tie[k+1] = tie[k]; --k; }
            tie[k+1] = v;
        }
        const int m4 = (int)sm4;
        float tsum = 0.f;
        for (int i = 0; i < m4 && i < tc; ++i) {
            const uint32_t j = tie[i];
            float dv = 0.f;
            for (int d = 0; d < EMB; ++d) dv += e[d] * uid[(size_t)j * EMB + d];
            tsum += dv;
        }
        out[b] = (sbelow + red[0] + tsum) / (float)KSEL;
    }
}

extern "C" void kernel_launch(void* const* d_in, const int* in_sizes, int n_in,
                              void* d_out, int out_size, void* d_ws, size_t ws_size,
                              hipStream_t stream) {
    const float* x     = (const float*)d_in[0];
    const float* uid   = (const float*)d_in[1];
    const float* iid_w = (const float*)d_in[2];
    const float* rp    = (const float*)d_in[3];
    float* out = (float*)d_out;

    char* ws = (char*)d_ws;
    float*    s_pre    = (float*)(ws + OFF_SPRE);
    float*    iid_emb  = (float*)(ws + OFF_IIDE);
    uint32_t* ghist    = (uint32_t*)(ws + OFF_GHIST);
    float*    sum_part = (float*)(ws + OFF_GHIST);     // overlay after scan1
    uint32_t* base16   = (uint32_t*)(ws + OFF_BASE16);
    uint32_t* prefix16 = (uint32_t*)(ws + OFF_PREFIX);
    uint32_t* m2       = (uint32_t*)(ws + OFF_M2);
    uint32_t* eq_cnt   = (uint32_t*)(ws + OFF_EQ);
    uint64_t* cand     = (uint64_t*)(ws + OFF_CAND);

    long long cap_ll = ((long long)ws_size - OFF_CAND) / (128LL * 8LL);
    int cap = (int)(cap_ll > 16384 ? 16384 : (cap_ll < 1 ? 1 : cap_ll));

    {
        const int n = (OFF_CAND - OFF_GHIST) / 4;
        zero_kernel<<<(n + 255) / 256, 256, 0, stream>>>((uint32_t*)(ws + OFF_GHIST), n);
    }
    prep_kernel<<<BATCH, 64, 0, stream>>>(x, iid_w, rp, uid, s_pre, iid_emb, base16);

    const int JC = 782;
    const int G  = 256;
    sweep1_kernel<<<G, 1024, 128 * 257 * 4, stream>>>(s_pre, uid, base16, ghist, JC);

    scan1_kernel<<<1, 128, 0, stream>>>(ghist, base16, prefix16, m2);

    sweep2_kernel<<<G, 1024, 65536 + 512 + 512 + 4096, stream>>>(s_pre, iid_emb, uid,
                                                                 prefix16, eq_cnt, sum_part,
                                                                 cand, cap, JC);

    final_kernel<<<BATCH, 256, 0, stream>>>(iid_emb, uid, m2, eq_cnt, sum_part,
                                            cand, cap, out);
}